// Round 2
// baseline (170.338 us; speedup 1.0000x reference)
//
#include <hip/hip_runtime.h>

namespace {
constexpr int IMG_W = 512, IMG_H = 512;
constexpr int TW = 32, TH = 64;
constexpr int IN_H = TH + 10;           // 74 staged rows
constexpr int IN_UNITS = 22;            // 44 px = 22 v4f units per row
constexpr int P1_TASKS = IN_H * IN_UNITS;   // 1628
constexpr int NTHREADS = 384;           // 6 waves
constexpr float C1c = 0.01f * 0.01f;
constexpr float C2c = 0.03f * 0.03f;

constexpr float GW[11] = {
    1.0283799e-03f, 7.5987582e-03f, 3.6000773e-02f, 1.0936069e-01f,
    2.1300554e-01f, 2.6601172e-01f, 2.1300554e-01f, 1.0936069e-01f,
    3.6000773e-02f, 7.5987582e-03f, 1.0283799e-03f
};

using v2f = __attribute__((ext_vector_type(2))) float;
using v4f = __attribute__((ext_vector_type(4))) float;

// In-place packed FMA, weight in SGPR pair: acc += w * a.
__device__ __forceinline__ void pkfma(v2f& acc, v2f w, v2f a) {
    asm("v_pk_fma_f32 %0, %1, %2, %0" : "+v"(acc) : "s"(w), "v"(a));
}
__device__ __forceinline__ v2f pkmul(v2f a, v2f b) {
    v2f d;
    asm("v_pk_mul_f32 %0, %1, %2" : "=v"(d) : "v"(a), "v"(b));
    return d;
}
__device__ __forceinline__ v2f bcast(float w) { v2f r; r.x = w; r.y = w; return r; }

// Unified plane: stride 32 v4f + rotate swizzle (col+row)&31.
__device__ __forceinline__ int pidx(int row, int col) {
    return row * 32 + ((col + row) & 31);
}

// Vertical 11-tap + SSIM for LEN consecutive output rows at one column.
template<int LEN>
__device__ __forceinline__ float vconv(const v4f* plane, int rb, int c3) {
    v2f mu[LEN], sx[LEN];
#pragma unroll
    for (int j = 0; j < LEN; ++j) { mu[j] = bcast(0.f); sx[j] = bcast(0.f); }
#pragma unroll
    for (int k = 0; k < LEN + 10; ++k) {
        const v4f q = plane[pidx(rb + k, c3)];
        v2f hm; hm.x = q.x; hm.y = q.y;
        v2f hx; hx.x = q.z; hx.y = q.w;
#pragma unroll
        for (int j = 0; j < LEN; ++j) {
            const int t = k - j;
            if (t >= 0 && t < 11) {
                const v2f w2 = bcast(GW[t]);
                pkfma(mu[j], w2, hm);
                pkfma(sx[j], w2, hx);
            }
        }
    }
    float lsum = 0.f;
#pragma unroll
    for (int j = 0; j < LEN; ++j) {
        const v2f musq = pkmul(mu[j], mu[j]);         // {mu1^2, mu2^2}
        const float mu12 = mu[j].x * mu[j].y;
        const float sden = musq.x + musq.y;           // mu1^2 + mu2^2
        const float s12v = sx[j].y - mu12;            // sigma12
        const float ssum = sx[j].x - sden;            // sigma1^2 + sigma2^2
        const float num = (2.f * mu12 + C1c) * (2.f * s12v + C2c);
        const float den = (sden + C1c) * (ssum + C2c);
        lsum += __fdividef(num, den);
    }
    return lsum;
}
}

// One 74x32-v4f plane (37.9 KB) serves both roles (time-sliced by barriers):
//   raw:  unit c of row r = pixels {x0e+2c, x0e+2c+1} packed {a0,b0,a1,b1}
//   h:    col c of row r  = (mu1, mu2, ss=conv(x^2+y^2), xy=conv(x*y))
// 4 blocks/CU x 6 waves = 24 waves/CU potential. (384,6): VGPR cap 85.
__global__ __launch_bounds__(NTHREADS, 6) void ssim_tile_kernel(
        const float* __restrict__ img1, const float* __restrict__ img2,
        double* __restrict__ acc)
{
    __shared__ v4f plane[IN_H * 32];
    __shared__ float wred[8];

    const int tid = threadIdx.x;
    const size_t base = (size_t)blockIdx.z * (IMG_W * IMG_H);
    const float* p1 = img1 + base;
    const float* p2 = img2 + base;
    const int x0e = blockIdx.x * TW - 6;    // even; window cols = pixels x0e..x0e+43
    const int y0  = blockIdx.y * TH - 5;

    // ---- Phase 1: global -> LDS, 2 pixels/thread, 74x22=1628 units, 5 rounds ----
    // Step of 384 units: r += 17, cf2 += 10 (wrap at 22: r += 18, cf2 -= 12).
    {
        int r   = tid / 22;
        int cf2 = tid - r * 22;
        int goff = (y0 + r) * IMG_W + x0e + 2 * cf2;
        const bool interior =
            blockIdx.x > 0 && blockIdx.x < gridDim.x - 1 &&
            blockIdx.y > 0 && blockIdx.y < gridDim.y - 1;
        if (interior) {
#pragma unroll
            for (int i = 0; i < 5; ++i) {
                if (i < 4 || tid < P1_TASKS - 4 * NTHREADS) {    // 92
                    const float2 a = *(const float2*)&p1[goff];
                    const float2 b = *(const float2*)&p2[goff];
                    v4f q; q.x = a.x; q.y = b.x; q.z = a.y; q.w = b.y;
                    plane[pidx(r, cf2)] = q;
                }
                const bool wrap = cf2 >= 12;
                cf2  += wrap ? -12 : 10;
                r    += wrap ? 18 : 17;
                goff += wrap ? 18 * IMG_W - 24 : 17 * IMG_W + 20;
            }
        } else {
#pragma unroll
            for (int i = 0; i < 5; ++i) {
                if (i < 4 || tid < P1_TASKS - 4 * NTHREADS) {
                    const int gy = y0 + r;
                    const int gx = x0e + 2 * cf2;
                    float a0 = 0.f, a1 = 0.f, b0 = 0.f, b1 = 0.f;
                    if (gy >= 0 && gy < IMG_H) {
                        if (gx >= 0 && gx < IMG_W)         { a0 = p1[goff];     b0 = p2[goff]; }
                        if (gx + 1 >= 0 && gx + 1 < IMG_W) { a1 = p1[goff + 1]; b1 = p2[goff + 1]; }
                    }
                    v4f q; q.x = a0; q.y = b0; q.z = a1; q.w = b1;
                    plane[pidx(r, cf2)] = q;
                }
                const bool wrap = cf2 >= 12;
                cf2  += wrap ? -12 : 10;
                r    += wrap ? 18 : 17;
                goff += wrap ? 18 * IMG_W - 24 : 17 * IMG_W + 20;
            }
        }
    }
    __syncthreads();

    // ---- Phase 2: horizontal 11-tap, scatter form ----
    // 74 rows x 4 col-groups (8 outputs each) = 296 tasks; single pass, tid<296.
    // Window col k (v2f) = pixel x0e+8g+k; output j taps t = k - j - 1.
    v2f mu8[8], sx8[8];
    const int rA = tid >> 2;
    const int gA = tid & 3;
    const bool act2 = tid < 296;
    if (act2) {
#pragma unroll
        for (int j = 0; j < 8; ++j) { mu8[j] = bcast(0.f); sx8[j] = bcast(0.f); }
        const int rowb = rA * 32;
        const int cb   = gA * 4 + rA;            // rotation base
#pragma unroll
        for (int m = 0; m < 10; ++m) {
            const v4f q = plane[rowb + ((cb + m) & 31)];
#pragma unroll
            for (int half = 0; half < 2; ++half) {
                const int k = 2 * m + half;
                v2f v;
                v.x = half ? q.z : q.x;
                v.y = half ? q.w : q.y;
                const v2f a2 = pkmul(v, v);
                v2f sx;                          // {x^2+y^2, x*y}
                sx.x = a2.x + a2.y;
                sx.y = v.x * v.y;
#pragma unroll
                for (int j = 0; j < 8; ++j) {
                    const int t = k - j - 1;
                    if (t >= 0 && t < 11) {
                        const v2f w2 = bcast(GW[t]);
                        pkfma(mu8[j], w2, v);
                        pkfma(sx8[j], w2, sx);
                    }
                }
            }
        }
    }
    __syncthreads();            // all raw-plane reads done; safe to overwrite
    if (act2) {
#pragma unroll
        for (int j = 0; j < 8; ++j) {
            v4f q;
            q.x = mu8[j].x; q.y = mu8[j].y;
            q.z = sx8[j].x; q.w = sx8[j].y;
            plane[pidx(rA, 8 * gA + j)] = q;
        }
    }
    __syncthreads();

    // ---- Phase 3: vertical 11-tap + SSIM ----
    // 12 row-groups x 32 cols = 384 threads. Groups 0-3: 6 rows, 4-11: 5 rows.
    // Split at tid=128 = wave boundary -> wave-uniform branch.
    const int c3 = tid & 31;
    const int gi = tid >> 5;
    float lsum;
    if (gi < 4) lsum = vconv<6>(plane, 6 * gi, c3);
    else        lsum = vconv<5>(plane, 24 + 5 * (gi - 4), c3);

    // ---- Phase 4: block reduce -> double atomic into 256 ws slots ----
#pragma unroll
    for (int off = 32; off > 0; off >>= 1)
        lsum += __shfl_down(lsum, off, 64);
    if ((tid & 63) == 0) wred[tid >> 6] = lsum;
    __syncthreads();
    if (tid == 0) {
        const int bid = (blockIdx.z * gridDim.y + blockIdx.y) * gridDim.x + blockIdx.x;
        unsafeAtomicAdd(&acc[bid & 255],
                        (double)(wred[0] + wred[1] + wred[2] +
                                 wred[3] + wred[4] + wred[5]));
    }
}

__global__ __launch_bounds__(256) void ssim_final_kernel(
        const double* __restrict__ acc, float* __restrict__ out, double inv_total)
{
    const int tid = threadIdx.x;
    double a = acc[tid];
#pragma unroll
    for (int off = 32; off > 0; off >>= 1)
        a += __shfl_down(a, off, 64);
    __shared__ double ws[4];
    if ((tid & 63) == 0) ws[tid >> 6] = a;
    __syncthreads();
    if (tid == 0)
        out[0] = (float)((ws[0] + ws[1] + ws[2] + ws[3]) * inv_total);
}

extern "C" void kernel_launch(void* const* d_in, const int* in_sizes, int n_in,
                              void* d_out, int out_size, void* d_ws, size_t ws_size,
                              hipStream_t stream)
{
    const float* img1 = (const float*)d_in[0];
    const float* img2 = (const float*)d_in[1];
    double* acc = (double*)d_ws;

    hipMemsetAsync(d_ws, 0, 256 * sizeof(double), stream);

    const int nch = in_sizes[0] / (IMG_W * IMG_H);      // 16*3 = 48
    dim3 grid(IMG_W / TW, IMG_H / TH, nch);             // 16 x 8 x 48
    ssim_tile_kernel<<<grid, NTHREADS, 0, stream>>>(img1, img2, acc);

    const double inv_total = 1.0 / (double)in_sizes[0];
    ssim_final_kernel<<<1, 256, 0, stream>>>(acc, (float*)d_out, inv_total);
}

// Round 3
// 164.266 us; speedup vs baseline: 1.0370x; 1.0370x over previous
//
#include <hip/hip_runtime.h>

namespace {
constexpr int IMG_W = 512, IMG_H = 512;
constexpr int TW = 32, TH = 32;
constexpr int IN_H = TH + 10;           // 42 staged rows
constexpr float C1c = 0.01f * 0.01f;
constexpr float C2c = 0.03f * 0.03f;

constexpr float GW[11] = {
    1.0283799e-03f, 7.5987582e-03f, 3.6000773e-02f, 1.0936069e-01f,
    2.1300554e-01f, 2.6601172e-01f, 2.1300554e-01f, 1.0936069e-01f,
    3.6000773e-02f, 7.5987582e-03f, 1.0283799e-03f
};

using v2f = __attribute__((ext_vector_type(2))) float;
using v4f = __attribute__((ext_vector_type(4))) float;

// In-place packed FMA, weight in SGPR pair: acc += w * a.
__device__ __forceinline__ void pkfma(v2f& acc, v2f w, v2f a) {
    asm("v_pk_fma_f32 %0, %1, %2, %0" : "+v"(acc) : "s"(w), "v"(a));
}
// d = a*b + c (all VGPR pairs).
__device__ __forceinline__ v2f pkfma3(v2f a, v2f b, v2f c) {
    v2f d;
    asm("v_pk_fma_f32 %0, %1, %2, %3" : "=v"(d) : "v"(a), "v"(b), "v"(c));
    return d;
}
__device__ __forceinline__ v2f pkmul(v2f a, v2f b) {
    v2f d;
    asm("v_pk_mul_f32 %0, %1, %2" : "=v"(d) : "v"(a), "v"(b));
    return d;
}
__device__ __forceinline__ v2f pkadd(v2f a, v2f b) {
    v2f d;
    asm("v_pk_add_f32 %0, %1, %2" : "=v"(d) : "v"(a), "v"(b));
    return d;
}
__device__ __forceinline__ v2f bcast(float w) { v2f r; r.x = w; r.y = w; return r; }
}

// LDS union (time-sliced by barriers), 21.5 KB -> 7 blocks/CU:
//   raw: v4f unit c of row r = pixels {x0e+2c, x0e+2c+1} packed {a0,b0,a1,b1},
//        row stride 23 v4f (pad col breaks power-of-2).
//   h:   pixel-PAIR planes, entry e=(row*16+pc)*2: A={mu1_0,mu1_1,mu2_0,mu2_1},
//        e+1: B={ss_0,ss_1,xy_0,xy_1}  (ss=conv(x^2+y^2), xy=conv(x*y)).
__global__ __launch_bounds__(256, 6) void ssim_tile_kernel(
        const float* __restrict__ img1, const float* __restrict__ img2,
        double* __restrict__ acc)
{
    union SharedU {
        v4f raw[IN_H * 23];          // 966 v4f = 15456 B
        v4f h  [IN_H * 16 * 2];      // 1344 v4f = 21504 B
    };
    __shared__ SharedU u;
    __shared__ float wred[4];

    const int tid = threadIdx.x;
    const size_t base = (size_t)blockIdx.z * (IMG_W * IMG_H);
    const float* p1 = img1 + base;
    const float* p2 = img2 + base;
    const int x0e = blockIdx.x * TW - 6;    // even; window cols = pixels x0e..x0e+43
    const int y0  = blockIdx.y * TH - 5;

    // ---- Phase 1: global -> LDS, 2 pixels/thread, 42x22=924 units, 4 rounds ----
    {
        v4f* s12v4 = u.raw;
        int r   = tid / 22;
        int cf2 = tid - r * 22;
        int goff = (y0 + r) * IMG_W + x0e + 2 * cf2;
        int soff = r * 23 + cf2;
        const bool interior =
            blockIdx.x > 0 && blockIdx.x < gridDim.x - 1 &&
            blockIdx.y > 0 && blockIdx.y < gridDim.y - 1;
        if (interior) {
#pragma unroll
            for (int i = 0; i < 4; ++i) {
                if (i < 3 || tid < 924 - 3 * 256) {     // 156
                    const float2 a = *(const float2*)&p1[goff];
                    const float2 b = *(const float2*)&p2[goff];
                    v4f q; q.x = a.x; q.y = b.x; q.z = a.y; q.w = b.y;
                    s12v4[soff] = q;
                }
                const bool wrap = cf2 + 14 >= 22;
                cf2  += wrap ? -8 : 14;
                r    += wrap ? 12 : 11;
                goff += wrap ? 12 * IMG_W - 16 : 11 * IMG_W + 28;
                soff += wrap ? 12 * 23 - 8     : 11 * 23 + 14;
            }
        } else {
#pragma unroll
            for (int i = 0; i < 4; ++i) {
                if (i < 3 || tid < 924 - 3 * 256) {
                    const int gy = y0 + r;
                    const int gx = x0e + 2 * cf2;
                    float a0 = 0.f, a1 = 0.f, b0 = 0.f, b1 = 0.f;
                    if (gy >= 0 && gy < IMG_H) {
                        if (gx >= 0 && gx < IMG_W)         { a0 = p1[goff];     b0 = p2[goff]; }
                        if (gx + 1 >= 0 && gx + 1 < IMG_W) { a1 = p1[goff + 1]; b1 = p2[goff + 1]; }
                    }
                    v4f q; q.x = a0; q.y = b0; q.z = a1; q.w = b1;
                    s12v4[soff] = q;
                }
                const bool wrap = cf2 + 14 >= 22;
                cf2  += wrap ? -8 : 14;
                r    += wrap ? 12 : 11;
                goff += wrap ? 12 * IMG_W - 16 : 11 * IMG_W + 28;
                soff += wrap ? 12 * 23 - 8     : 11 * 23 + 14;
            }
        }
    }
    __syncthreads();

    // ---- Phase 2: horizontal 11-tap, scatter form ----
    // 42 rows x 4 col-groups x 8 outputs = 168 active threads.
    // v2f window col k = pixel x0e + 8g + k; output j taps t = k - j - 1.
    v2f mu8[8], sx8[8];     // mu8 = {mu1,mu2}; sx8 = {ss, xy}
    const int rA = tid >> 2;
    const int gA = tid & 3;
    const bool act2 = tid < 168;
    if (act2) {
#pragma unroll
        for (int j = 0; j < 8; ++j) { mu8[j] = bcast(0.f); sx8[j] = bcast(0.f); }
        const v4f* srow = u.raw + (rA * 23 + gA * 4);
#pragma unroll
        for (int m = 0; m < 10; ++m) {
            const v4f q = srow[m];
            const v2f* qh = (const v2f*)&q;       // subregister halves, no movs
#pragma unroll
            for (int half = 0; half < 2; ++half) {
                const int k = 2 * m + half;
                const v2f v = qh[half];
                const v2f a2 = pkmul(v, v);
                v2f sx;                           // {x^2+y^2, x*y}
                sx.x = a2.x + a2.y;
                sx.y = v.x * v.y;
#pragma unroll
                for (int j = 0; j < 8; ++j) {
                    const int t = k - j - 1;
                    if (t >= 0 && t < 11) {
                        const v2f w2 = bcast(GW[t]);
                        pkfma(mu8[j], w2, v);
                        pkfma(sx8[j], w2, sx);
                    }
                }
            }
        }
    }
    __syncthreads();            // all raw reads done; safe to overwrite
    if (act2) {
        // transpose {a,b}-packed accs into pixel-pair planes
#pragma unroll
        for (int jp = 0; jp < 4; ++jp) {
            const int j0 = 2 * jp, j1 = 2 * jp + 1;
            v4f A; A.x = mu8[j0].x; A.y = mu8[j1].x; A.z = mu8[j0].y; A.w = mu8[j1].y;
            v4f B; B.x = sx8[j0].x; B.y = sx8[j1].x; B.z = sx8[j0].y; B.w = sx8[j1].y;
            const int e = (rA * 16 + 4 * gA + jp) * 2;
            u.h[e]     = A;
            u.h[e + 1] = B;
        }
    }
    __syncthreads();

    // ---- Phase 3: vertical 11-tap + SSIM, pixel-pair packed, 128 threads ----
    // 16 pair-cols x 8 row-groups of 4 output rows; output px col = x0 + 2pc+{0,1}.
    float lsum = 0.f;
    if (tid < 128) {
        const int pc = tid & 15;
        const int rb = (tid >> 4) * 4;
        v2f m1[4], m2[4], ssA[4], xyA[4];
#pragma unroll
        for (int j = 0; j < 4; ++j) {
            m1[j] = bcast(0.f); m2[j] = bcast(0.f);
            ssA[j] = bcast(0.f); xyA[j] = bcast(0.f);
        }
#pragma unroll
        for (int k = 0; k < 14; ++k) {
            const int e = ((rb + k) * 16 + pc) * 2;
            const v4f A = u.h[e];
            const v4f B = u.h[e + 1];
            const v2f* ah = (const v2f*)&A;
            const v2f* bh = (const v2f*)&B;
#pragma unroll
            for (int j = 0; j < 4; ++j) {
                const int t = k - j;
                if (t >= 0 && t < 11) {
                    const v2f w2 = bcast(GW[t]);
                    pkfma(m1[j],  w2, ah[0]);     // mu1 pair
                    pkfma(m2[j],  w2, ah[1]);     // mu2 pair
                    pkfma(ssA[j], w2, bh[0]);     // ss  pair
                    pkfma(xyA[j], w2, bh[1]);     // xy  pair
                }
            }
        }
        const v2f two  = bcast(2.f);
        const v2f c1p  = bcast(C1c);
        const v2f c2p  = bcast(C2c);
        const v2f neg1 = bcast(-1.f);
#pragma unroll
        for (int j = 0; j < 4; ++j) {
            const v2f mu12 = pkmul(m1[j], m2[j]);
            const v2f sden = pkadd(pkmul(m1[j], m1[j]), pkmul(m2[j], m2[j]));
            const v2f s12  = pkfma3(mu12, neg1, xyA[j]);   // xy - mu1*mu2
            const v2f ssum = pkfma3(sden, neg1, ssA[j]);   // ss - (mu1^2+mu2^2)
            const v2f num  = pkmul(pkfma3(mu12, two, c1p), pkfma3(s12, two, c2p));
            const v2f den  = pkmul(pkadd(sden, c1p), pkadd(ssum, c2p));
            lsum += __fdividef(num.x, den.x) + __fdividef(num.y, den.y);
        }
    }

    // ---- Phase 4: block reduce -> double atomic into 256 ws slots ----
#pragma unroll
    for (int off = 32; off > 0; off >>= 1)
        lsum += __shfl_down(lsum, off, 64);
    if ((tid & 63) == 0) wred[tid >> 6] = lsum;
    __syncthreads();
    if (tid == 0) {
        const int bid = (blockIdx.z * gridDim.y + blockIdx.y) * gridDim.x + blockIdx.x;
        unsafeAtomicAdd(&acc[bid & 255],
                        (double)(wred[0] + wred[1] + wred[2] + wred[3]));
    }
}

__global__ __launch_bounds__(256) void ssim_final_kernel(
        const double* __restrict__ acc, float* __restrict__ out, double inv_total)
{
    const int tid = threadIdx.x;
    double a = acc[tid];
#pragma unroll
    for (int off = 32; off > 0; off >>= 1)
        a += __shfl_down(a, off, 64);
    __shared__ double ws[4];
    if ((tid & 63) == 0) ws[tid >> 6] = a;
    __syncthreads();
    if (tid == 0)
        out[0] = (float)((ws[0] + ws[1] + ws[2] + ws[3]) * inv_total);
}

extern "C" void kernel_launch(void* const* d_in, const int* in_sizes, int n_in,
                              void* d_out, int out_size, void* d_ws, size_t ws_size,
                              hipStream_t stream)
{
    const float* img1 = (const float*)d_in[0];
    const float* img2 = (const float*)d_in[1];
    double* acc = (double*)d_ws;

    hipMemsetAsync(d_ws, 0, 256 * sizeof(double), stream);

    const int nch = in_sizes[0] / (IMG_W * IMG_H);      // 16*3 = 48
    dim3 grid(IMG_W / TW, IMG_H / TH, nch);             // 16 x 16 x 48
    ssim_tile_kernel<<<grid, 256, 0, stream>>>(img1, img2, acc);

    const double inv_total = 1.0 / (double)in_sizes[0];
    ssim_final_kernel<<<1, 256, 0, stream>>>(acc, (float*)d_out, inv_total);
}

// Round 4
// 152.521 us; speedup vs baseline: 1.1168x; 1.0770x over previous
//
#include <hip/hip_runtime.h>

namespace {
constexpr int IMG_W = 512, IMG_H = 512;
constexpr int TW = 32, TH = 32;
constexpr int IN_H = TH + 10;           // 42 staged rows
constexpr float C1c = 0.01f * 0.01f;
constexpr float C2c = 0.03f * 0.03f;

constexpr float GW[11] = {
    1.0283799e-03f, 7.5987582e-03f, 3.6000773e-02f, 1.0936069e-01f,
    2.1300554e-01f, 2.6601172e-01f, 2.1300554e-01f, 1.0936069e-01f,
    3.6000773e-02f, 7.5987582e-03f, 1.0283799e-03f
};

using v2f = __attribute__((ext_vector_type(2))) float;
using v4f = __attribute__((ext_vector_type(4))) float;

// In-place packed FMA, weight in SGPR pair: acc += w * a.
__device__ __forceinline__ void pkfma(v2f& acc, v2f w, v2f a) {
    asm("v_pk_fma_f32 %0, %1, %2, %0" : "+v"(acc) : "s"(w), "v"(a));
}
// d = a*b + c (all VGPR pairs).
__device__ __forceinline__ v2f pkfma3(v2f a, v2f b, v2f c) {
    v2f d;
    asm("v_pk_fma_f32 %0, %1, %2, %3" : "=v"(d) : "v"(a), "v"(b), "v"(c));
    return d;
}
__device__ __forceinline__ v2f pkmul(v2f a, v2f b) {
    v2f d;
    asm("v_pk_mul_f32 %0, %1, %2" : "=v"(d) : "v"(a), "v"(b));
    return d;
}
__device__ __forceinline__ v2f pkadd(v2f a, v2f b) {
    v2f d;
    asm("v_pk_add_f32 %0, %1, %2" : "=v"(d) : "v"(a), "v"(b));
    return d;
}
__device__ __forceinline__ v2f bcast(float w) { v2f r; r.x = w; r.y = w; return r; }

// h-plane rotate swizzle: 16 v4f per row, entry = row*16 + ((pc+row)&15).
// Bank group = ((pc+row) mod 8)*4 -> P2 writes (pc=4gA+jp, row=rA) and
// P3 reads (pc=tid&15, row=rb+k) both spread 8 lanes per 4-bank group.
__device__ __forceinline__ int hswz(int row, int pc) {
    return row * 16 + ((pc + row) & 15);
}
}

// LDS union (time-sliced by barriers), 21.5 KB -> 7 blocks/CU:
//   raw: v4f unit c of row r = pixels {x0e+2c, x0e+2c+1} packed {a0,b0,a1,b1},
//        row stride 23 v4f (odd stride -> uniform banks in all phases).
//   hA:  pixel-pair {mu1_0,mu1_1,mu2_0,mu2_1}, rotate-swizzled.
//   hB:  pixel-pair {ss_0,ss_1,xy_0,xy_1}   (ss=conv(x^2+y^2), xy=conv(x*y)).
__global__ __launch_bounds__(256, 6) void ssim_tile_kernel(
        const float* __restrict__ img1, const float* __restrict__ img2,
        double* __restrict__ acc)
{
    union SharedU {
        v4f raw[IN_H * 23];              // 966 v4f = 15456 B
        struct {
            v4f hA[IN_H * 16];           // 672 v4f = 10752 B
            v4f hB[IN_H * 16];           // 672 v4f = 10752 B
        } h;                             // 21504 B total
    };
    __shared__ SharedU u;
    __shared__ float wred[4];

    const int tid = threadIdx.x;
    const size_t base = (size_t)blockIdx.z * (IMG_W * IMG_H);
    const float* p1 = img1 + base;
    const float* p2 = img2 + base;
    const int x0e = blockIdx.x * TW - 6;    // even; window cols = pixels x0e..x0e+43
    const int y0  = blockIdx.y * TH - 5;

    // ---- Phase 1: global -> LDS, 2 pixels/thread, 42x22=924 units, 4 rounds ----
    {
        v4f* s12v4 = u.raw;
        int r   = tid / 22;
        int cf2 = tid - r * 22;
        int goff = (y0 + r) * IMG_W + x0e + 2 * cf2;
        int soff = r * 23 + cf2;
        const bool interior =
            blockIdx.x > 0 && blockIdx.x < gridDim.x - 1 &&
            blockIdx.y > 0 && blockIdx.y < gridDim.y - 1;
        if (interior) {
#pragma unroll
            for (int i = 0; i < 4; ++i) {
                if (i < 3 || tid < 924 - 3 * 256) {     // 156
                    const float2 a = *(const float2*)&p1[goff];
                    const float2 b = *(const float2*)&p2[goff];
                    v4f q; q.x = a.x; q.y = b.x; q.z = a.y; q.w = b.y;
                    s12v4[soff] = q;
                }
                const bool wrap = cf2 + 14 >= 22;
                cf2  += wrap ? -8 : 14;
                r    += wrap ? 12 : 11;
                goff += wrap ? 12 * IMG_W - 16 : 11 * IMG_W + 28;
                soff += wrap ? 12 * 23 - 8     : 11 * 23 + 14;
            }
        } else {
#pragma unroll
            for (int i = 0; i < 4; ++i) {
                if (i < 3 || tid < 924 - 3 * 256) {
                    const int gy = y0 + r;
                    const int gx = x0e + 2 * cf2;
                    float a0 = 0.f, a1 = 0.f, b0 = 0.f, b1 = 0.f;
                    if (gy >= 0 && gy < IMG_H) {
                        if (gx >= 0 && gx < IMG_W)         { a0 = p1[goff];     b0 = p2[goff]; }
                        if (gx + 1 >= 0 && gx + 1 < IMG_W) { a1 = p1[goff + 1]; b1 = p2[goff + 1]; }
                    }
                    v4f q; q.x = a0; q.y = b0; q.z = a1; q.w = b1;
                    s12v4[soff] = q;
                }
                const bool wrap = cf2 + 14 >= 22;
                cf2  += wrap ? -8 : 14;
                r    += wrap ? 12 : 11;
                goff += wrap ? 12 * IMG_W - 16 : 11 * IMG_W + 28;
                soff += wrap ? 12 * 23 - 8     : 11 * 23 + 14;
            }
        }
    }
    __syncthreads();

    // ---- Phase 2: horizontal 11-tap, scatter form ----
    // 42 rows x 4 col-groups x 8 outputs = 168 active threads.
    // v2f window col k = pixel x0e + 8g + k; output j taps t = k - j - 1.
    v2f mu8[8], sx8[8];     // mu8 = {mu1,mu2}; sx8 = {ss, xy}
    const int rA = tid >> 2;
    const int gA = tid & 3;
    const bool act2 = tid < 168;
    if (act2) {
#pragma unroll
        for (int j = 0; j < 8; ++j) { mu8[j] = bcast(0.f); sx8[j] = bcast(0.f); }
        const v4f* srow = u.raw + (rA * 23 + gA * 4);
#pragma unroll
        for (int m = 0; m < 10; ++m) {
            const v4f q = srow[m];
            const v2f* qh = (const v2f*)&q;       // subregister halves, no movs
#pragma unroll
            for (int half = 0; half < 2; ++half) {
                const int k = 2 * m + half;
                const v2f v = qh[half];
                const v2f a2 = pkmul(v, v);
                v2f sx;                           // {x^2+y^2, x*y}
                sx.x = a2.x + a2.y;
                sx.y = v.x * v.y;
#pragma unroll
                for (int j = 0; j < 8; ++j) {
                    const int t = k - j - 1;
                    if (t >= 0 && t < 11) {
                        const v2f w2 = bcast(GW[t]);
                        pkfma(mu8[j], w2, v);
                        pkfma(sx8[j], w2, sx);
                    }
                }
            }
        }
    }
    __syncthreads();            // all raw reads done; safe to overwrite
    if (act2) {
        // transpose {a,b}-packed accs into pixel-pair planes
#pragma unroll
        for (int jp = 0; jp < 4; ++jp) {
            const int j0 = 2 * jp, j1 = 2 * jp + 1;
            v4f A; A.x = mu8[j0].x; A.y = mu8[j1].x; A.z = mu8[j0].y; A.w = mu8[j1].y;
            v4f B; B.x = sx8[j0].x; B.y = sx8[j1].x; B.z = sx8[j0].y; B.w = sx8[j1].y;
            const int e = hswz(rA, 4 * gA + jp);
            u.h.hA[e] = A;
            u.h.hB[e] = B;
        }
    }
    __syncthreads();

    // ---- Phase 3: vertical 11-tap + SSIM, pixel-pair packed, 128 threads ----
    // 16 pair-cols x 8 row-groups of 4 output rows; output px col = x0 + 2pc+{0,1}.
    float lsum = 0.f;
    if (tid < 128) {
        const int pc = tid & 15;
        const int rb = (tid >> 4) * 4;
        v2f m1[4], m2[4], ssA[4], xyA[4];
#pragma unroll
        for (int j = 0; j < 4; ++j) {
            m1[j] = bcast(0.f); m2[j] = bcast(0.f);
            ssA[j] = bcast(0.f); xyA[j] = bcast(0.f);
        }
#pragma unroll
        for (int k = 0; k < 14; ++k) {
            const int e = hswz(rb + k, pc);
            const v4f A = u.h.hA[e];
            const v4f B = u.h.hB[e];
            const v2f* ah = (const v2f*)&A;
            const v2f* bh = (const v2f*)&B;
#pragma unroll
            for (int j = 0; j < 4; ++j) {
                const int t = k - j;
                if (t >= 0 && t < 11) {
                    const v2f w2 = bcast(GW[t]);
                    pkfma(m1[j],  w2, ah[0]);     // mu1 pair
                    pkfma(m2[j],  w2, ah[1]);     // mu2 pair
                    pkfma(ssA[j], w2, bh[0]);     // ss  pair
                    pkfma(xyA[j], w2, bh[1]);     // xy  pair
                }
            }
        }
        const v2f two  = bcast(2.f);
        const v2f c1p  = bcast(C1c);
        const v2f c2p  = bcast(C2c);
        const v2f neg1 = bcast(-1.f);
#pragma unroll
        for (int j = 0; j < 4; ++j) {
            const v2f mu12 = pkmul(m1[j], m2[j]);
            const v2f sden = pkadd(pkmul(m1[j], m1[j]), pkmul(m2[j], m2[j]));
            const v2f s12  = pkfma3(mu12, neg1, xyA[j]);   // xy - mu1*mu2
            const v2f ssum = pkfma3(sden, neg1, ssA[j]);   // ss - (mu1^2+mu2^2)
            const v2f num  = pkmul(pkfma3(mu12, two, c1p), pkfma3(s12, two, c2p));
            const v2f den  = pkmul(pkadd(sden, c1p), pkadd(ssum, c2p));
            lsum += __fdividef(num.x, den.x) + __fdividef(num.y, den.y);
        }
    }

    // ---- Phase 4: block reduce -> double atomic into 256 ws slots ----
#pragma unroll
    for (int off = 32; off > 0; off >>= 1)
        lsum += __shfl_down(lsum, off, 64);
    if ((tid & 63) == 0) wred[tid >> 6] = lsum;
    __syncthreads();
    if (tid == 0) {
        const int bid = (blockIdx.z * gridDim.y + blockIdx.y) * gridDim.x + blockIdx.x;
        unsafeAtomicAdd(&acc[bid & 255],
                        (double)(wred[0] + wred[1] + wred[2] + wred[3]));
    }
}

__global__ __launch_bounds__(256) void ssim_final_kernel(
        const double* __restrict__ acc, float* __restrict__ out, double inv_total)
{
    const int tid = threadIdx.x;
    double a = acc[tid];
#pragma unroll
    for (int off = 32; off > 0; off >>= 1)
        a += __shfl_down(a, off, 64);
    __shared__ double ws[4];
    if ((tid & 63) == 0) ws[tid >> 6] = a;
    __syncthreads();
    if (tid == 0)
        out[0] = (float)((ws[0] + ws[1] + ws[2] + ws[3]) * inv_total);
}

extern "C" void kernel_launch(void* const* d_in, const int* in_sizes, int n_in,
                              void* d_out, int out_size, void* d_ws, size_t ws_size,
                              hipStream_t stream)
{
    const float* img1 = (const float*)d_in[0];
    const float* img2 = (const float*)d_in[1];
    double* acc = (double*)d_ws;

    hipMemsetAsync(d_ws, 0, 256 * sizeof(double), stream);

    const int nch = in_sizes[0] / (IMG_W * IMG_H);      // 16*3 = 48
    dim3 grid(IMG_W / TW, IMG_H / TH, nch);             // 16 x 16 x 48
    ssim_tile_kernel<<<grid, 256, 0, stream>>>(img1, img2, acc);

    const double inv_total = 1.0 / (double)in_sizes[0];
    ssim_final_kernel<<<1, 256, 0, stream>>>(acc, (float*)d_out, inv_total);
}